// Round 2
// baseline (265.219 us; speedup 1.0000x reference)
//
#include <hip/hip_runtime.h>

#define NROWS 8000
#define DDIM 9
#define NCOL4 (NROWS / 4)      // 2000 float4 per output row
#define NCHUNK 125             // 8000 rows / 64 rows-per-wave
#define ROWS_PER_BLK 5         // K2: contiguous rows per block -> 1600 blocks
#define NPASS 7                // full 256-wide column passes (7*256 = 1792)
#define TAIL 208               // remaining float4 columns (2000 - 1792)

typedef float f32x4 __attribute__((ext_vector_type(4)));

// ---------------------------------------------------------------------------
// K1: one wave per 64-row chunk. Per row: s = sum_j ((x-c)/a)^2, f = x.w+b.
// Wave-level inclusive scan (shuffles, no barriers) -> local cumsums cs1,cs2;
// lane 63 writes chunk totals. (Unchanged, verified.)
// ---------------------------------------------------------------------------
__global__ __launch_bounds__(256)
void anfis_rows(const float* __restrict__ x,
                const float* __restrict__ a1p, const float* __restrict__ c1p,
                const float* __restrict__ a2p, const float* __restrict__ c2p,
                const float* __restrict__ w_fc1, const float* __restrict__ b_fc1,
                const float* __restrict__ w_fc2, const float* __restrict__ b_fc2,
                float* __restrict__ cs1o, float* __restrict__ cs2o,
                float2* __restrict__ f12o,
                float* __restrict__ t1o, float* __restrict__ t2o) {
    const int wid  = (blockIdx.x * 256 + threadIdx.x) >> 6;   // chunk id
    const int lane = threadIdx.x & 63;
    if (wid >= NCHUNK) return;
    const int r = wid * 64 + lane;

    const float inv_a1 = 1.0f / a1p[0];
    const float c1 = c1p[0];
    const float inv_a2 = 1.0f / a2p[0];
    const float c2 = c2p[0];

    float s1 = 0.f, s2 = 0.f, d1 = 0.f, d2 = 0.f;
#pragma unroll
    for (int j = 0; j < DDIM; ++j) {
        float xv = x[r * DDIM + j];
        float u1 = (xv - c1) * inv_a1;
        float u2 = (xv - c2) * inv_a2;
        s1 += u1 * u1;
        s2 += u2 * u2;
        d1 += xv * w_fc1[j];
        d2 += xv * w_fc2[j];
    }
    f12o[r] = make_float2(d1 + b_fc1[0], d2 + b_fc2[0]);

    // inclusive wave scan over 64 lanes
#pragma unroll
    for (int d = 1; d < 64; d <<= 1) {
        float n1 = __shfl_up(s1, d, 64);
        float n2 = __shfl_up(s2, d, 64);
        if (lane >= d) { s1 += n1; s2 += n2; }
    }
    cs1o[r] = s1;
    cs2o[r] = s2;
    if (lane == 63) { t1o[wid] = s1; t2o[wid] = s2; }
}

// ---------------------------------------------------------------------------
// K1b: per-column normalized weight u = w1_bar (w2_bar = 1-u, used via
// algebra in K2). 8 blocks x 256 threads; each block redundantly scans the
// 125 chunk totals with a single-wave shuffle scan (1 barrier), then:
//   a = cs1[j]+P1[chunk], b = cs2[j]+P2[chunk], u = 1/(1+exp(a-b))
// Writes u4[2000] (f32x4) to workspace. All transcendentals leave K2.
// ---------------------------------------------------------------------------
__global__ __launch_bounds__(256)
void anfis_cols(const float* __restrict__ cs1, const float* __restrict__ cs2,
                const float* __restrict__ t1, const float* __restrict__ t2,
                f32x4* __restrict__ u4) {
    __shared__ float sp1[128];             // exclusive chunk prefixes
    __shared__ float sp2[128];
    const int tid = threadIdx.x;

    if (tid < 64) {
        const int l = tid;
        float e10 = 0.f, e11 = 0.f, e20 = 0.f, e21 = 0.f;
        if (2 * l < NCHUNK)     { e10 = t1[2 * l];     e20 = t2[2 * l]; }
        if (2 * l + 1 < NCHUNK) { e11 = t1[2 * l + 1]; e21 = t2[2 * l + 1]; }
        const float p1 = e10 + e11, p2 = e20 + e21;   // pair sums
        float s1 = p1, s2 = p2;
#pragma unroll
        for (int d = 1; d < 64; d <<= 1) {
            float n1 = __shfl_up(s1, d, 64);
            float n2 = __shfl_up(s2, d, 64);
            if (l >= d) { s1 += n1; s2 += n2; }
        }
        const float ex1 = s1 - p1, ex2 = s2 - p2;     // exclusive pair prefix
        sp1[2 * l]     = ex1;        sp2[2 * l]     = ex2;
        sp1[2 * l + 1] = ex1 + e10;  sp2[2 * l + 1] = ex2 + e20;
    }
    __syncthreads();

    const int j4 = blockIdx.x * 256 + tid;
    if (j4 >= NCOL4) return;
    const int c = j4 >> 4;                   // chunk of these 4 columns

    f32x4 a = ((const f32x4*)cs1)[j4] + sp1[c];
    f32x4 b = ((const f32x4*)cs2)[j4] + sp2[c];
    f32x4 u;
#pragma unroll
    for (int q = 0; q < 4; ++q) {
        float e = expf(a[q] - b[q]);
        u[q] = 1.0f / (1.0f + e);            // w1_bar; w2_bar = 1-u
    }
    u4[j4] = u;
}

// ---------------------------------------------------------------------------
// K2: pure streaming store, maximally fill-like.
//   out[i][:] = f2[i] + (f1[i]-f2[i]) * u[:]
// 1600 blocks x 5 CONTIGUOUS rows each -> every block writes one 160 KB
// fully-sequential region. No LDS, no barriers, no transcendentals in-loop;
// u fragments live in 32 VGPRs loaded once per block; f12 row scalars are
// block-uniform loads. 40 unrolled fma+dwordx4 stores per thread.
// ---------------------------------------------------------------------------
__global__ __launch_bounds__(256)
void anfis_out(const float2* __restrict__ f12, const f32x4* __restrict__ u4,
               float* __restrict__ out) {
    const int tid = threadIdx.x;
    const int i0 = blockIdx.x * ROWS_PER_BLK;

    f32x4 ur[NPASS + 1];
#pragma unroll
    for (int p = 0; p < NPASS; ++p) ur[p] = u4[tid + p * 256];
    if (tid < TAIL) ur[NPASS] = u4[tid + NPASS * 256];

#pragma unroll
    for (int r = 0; r < ROWS_PER_BLK; ++r) {
        const float2 ab = f12[i0 + r];       // block-uniform
        const float d = ab.x - ab.y;
        f32x4* row = (f32x4*)out + (size_t)(i0 + r) * NCOL4;
#pragma unroll
        for (int p = 0; p < NPASS; ++p)
            row[tid + p * 256] = d * ur[p] + ab.y;
        if (tid < TAIL)
            row[tid + NPASS * 256] = d * ur[NPASS] + ab.y;
    }
}

// ---------------------------------------------------------------------------
extern "C" void kernel_launch(void* const* d_in, const int* in_sizes, int n_in,
                              void* d_out, int out_size, void* d_ws, size_t ws_size,
                              hipStream_t stream) {
    const float* x     = (const float*)d_in[0];
    const float* a1    = (const float*)d_in[1];
    const float* c1    = (const float*)d_in[2];
    const float* a2    = (const float*)d_in[3];
    const float* c2    = (const float*)d_in[4];
    const float* w_fc1 = (const float*)d_in[5];
    const float* b_fc1 = (const float*)d_in[6];
    const float* w_fc2 = (const float*)d_in[7];
    const float* b_fc2 = (const float*)d_in[8];
    float* out = (float*)d_out;

    float* ws   = (float*)d_ws;          // ~161 KB used
    float* cs1  = ws;                    // [8000] local inclusive cumsums
    float* cs2  = ws + 8000;
    float2* f12 = (float2*)(ws + 16000); // [8000] float2
    float* t1   = ws + 32000;            // [125] chunk totals
    float* t2   = ws + 32125;
    f32x4* u4   = (f32x4*)(ws + 32256);  // [2000] f32x4 column weights

    anfis_rows<<<(NCHUNK * 64 + 255) / 256, 256, 0, stream>>>(
        x, a1, c1, a2, c2, w_fc1, b_fc1, w_fc2, b_fc2, cs1, cs2, f12, t1, t2);
    anfis_cols<<<(NCOL4 + 255) / 256, 256, 0, stream>>>(cs1, cs2, t1, t2, u4);
    anfis_out<<<NROWS / ROWS_PER_BLK, 256, 0, stream>>>(f12, u4, out);
}